// Round 15
// baseline (206.572 us; speedup 1.0000x reference)
//
#include <hip/hip_runtime.h>

typedef unsigned short u16;
typedef __attribute__((ext_vector_type(8))) short bf16x8;
typedef __attribute__((ext_vector_type(4))) float f32x4;

__device__ __forceinline__ float bf2f(u16 s) {
    return __uint_as_float(((unsigned)s) << 16);
}
__device__ __forceinline__ u16 f2bf(float f) {
    unsigned u = __float_as_uint(f);
    u += 0x7fff + ((u >> 16) & 1);   // RNE
    return (u16)(u >> 16);
}
__device__ __forceinline__ void unpack8(bf16x8 x, float* f) {
#pragma unroll
    for (int j = 0; j < 8; ++j) f[j] = bf2f((u16)x[j]);
}

// async 16B global -> LDS (linear dest: uniform base + lane*16)
__device__ __forceinline__ void gload16(const u16* g, u16* l) {
    __builtin_amdgcn_global_load_lds(
        (const __attribute__((address_space(1))) unsigned*)g,
        (__attribute__((address_space(3))) unsigned*)l, 16, 0, 0);
}

// q.k dot over 8 packed bf16; fdot2 when available.
__device__ __forceinline__ float dot8(bf16x8 a, bf16x8 b, float c) {
#if __has_builtin(__builtin_amdgcn_fdot2_f32_bf16)
    typedef __attribute__((ext_vector_type(2))) __bf16 bf16x2;
    union U { bf16x8 v; bf16x2 p[4]; };
    U ua, ub; ua.v = a; ub.v = b;
#pragma unroll
    for (int i = 0; i < 4; ++i)
        c = __builtin_amdgcn_fdot2_f32_bf16(ua.p[i], ub.p[i], c, false);
    return c;
#else
    float fa[8], fb[8];
    unpack8(a, fa); unpack8(b, fb);
#pragma unroll
    for (int j = 0; j < 8; ++j) c = fmaf(fa[j], fb[j], c);
    return c;
#endif
}

struct Ptr8 { const float* p[8]; };
struct PrepArgs { const float* w[8]; const float* b[8]; };

// ---------------------------------------------------------------------------
// FUSED setup kernel (unchanged from R14): histogram | weight prep | L1 GEMM
// ---------------------------------------------------------------------------
__global__ __launch_bounds__(256)
void setup_fused(const int* __restrict__ edst, int* __restrict__ deg, int E,
                 PrepArgs a, u16* __restrict__ Wt2, u16* __restrict__ Wt3,
                 float* __restrict__ b2, float* __restrict__ b3,
                 const float* __restrict__ X, Ptr8 wb,
                 u16* __restrict__ OUT, int N) {
    int b = blockIdx.x;
    int nh = (E + 255) / 256;
    if (b < nh) {
        int i = b * 256 + threadIdx.x;
        if (i < E) atomicAdd(&deg[edst[i]], 1);
        return;
    }
    b -= nh;
    if (b < 2304) {
        int z = b >> 8, rem = b & 255;
        int bx = rem & 15, by = rem >> 4;
        if (z == 8) {
            if (by != 0 || bx >= 9) return;
            int j = bx * 256 + threadIdx.x;
            if (j < 2048) b2[j] = a.b[j >> 9][j & 511];
            else if (j < 2304) { int jj = j - 2048; b3[jj] = a.b[4 + (jj >> 6)][jj & 63]; }
            return;
        }
        const float* in;
        u16* out;
        int Nw;
        if (z < 4) { in = a.w[z]; out = Wt2 + (size_t)z * 512 * 512; Nw = 512; }
        else {
            if (by >= 2) return;
            in = a.w[z]; out = Wt3 + (size_t)(z - 4) * 64 * 512; Nw = 64;
        }
        __shared__ float t[32][33];
        int kb = bx * 32, nb = by * 32;
        int tx = threadIdx.x & 31, ty = threadIdx.x >> 5;
#pragma unroll
        for (int r = ty; r < 32; r += 8)
            if (nb + tx < Nw)
                t[r][tx] = in[(size_t)(kb + r) * Nw + nb + tx];
        __syncthreads();
#pragma unroll
        for (int r = ty; r < 32; r += 8)
            if (nb + r < Nw)
                out[(size_t)(nb + r) * 512 + kb + tx] = f2bf(t[tx][r]);
        return;
    }
    b -= 2304;
    int wsel = threadIdx.x >> 6;
    int jj = (threadIdx.x & 63) * 8;
    const float* W = wb.p[wsel];
    const float* bb = wb.p[4 + wsel];
    float w[5][8], bs[8];
#pragma unroll
    for (int i = 0; i < 5; ++i)
#pragma unroll
        for (int j = 0; j < 8; ++j) w[i][j] = W[(size_t)i * 512 + jj + j];
#pragma unroll
    for (int j = 0; j < 8; ++j) bs[j] = bb[jj + j];
    int n0 = b * 32;
    int nend = (N - n0 < 32) ? (N - n0) : 32;
    for (int i = 0; i < nend; ++i) {
        int n = n0 + i;
        float xr[5];
#pragma unroll
        for (int k = 0; k < 5; ++k) xr[k] = X[(size_t)n * 5 + k];
        float acc[8];
#pragma unroll
        for (int j = 0; j < 8; ++j) acc[j] = bs[j];
#pragma unroll
        for (int k = 0; k < 5; ++k)
#pragma unroll
            for (int j = 0; j < 8; ++j) acc[j] = fmaf(xr[k], w[k][j], acc[j]);
        bf16x8 o;
#pragma unroll
        for (int j = 0; j < 8; ++j) o[j] = (short)f2bf(acc[j]);
        *(bf16x8*)(OUT + (size_t)n * 2048 + wsel * 512 + jj) = o;
    }
}

// ---------------------------------------------------------------------------
// bf16 MFMA GEMM (unchanged from R14: single-buffer + K-phase stagger +
// m204 XCD chunking + pre-swizzled-source global_load_lds)
// ---------------------------------------------------------------------------
template <int TN, int GN>
__global__ __launch_bounds__(256)
void gemm_bf16(const u16* __restrict__ A, const u16* __restrict__ Bt,
               const float* __restrict__ bias, u16* __restrict__ C,
               int M, int Ncols, int K) {
    constexpr int TM = 128, BK = 64;
    constexpr int MFR = (TN == 128) ? 4 : 2;
    constexpr int NFR = 4;
    constexpr int ACH = TM * BK / (256 * 8);
    constexpr int BCH = TN * BK / (256 * 8);

    __shared__ u16 As[TM * BK];
    __shared__ u16 Bs[TN * BK];

    int nwg = gridDim.x;
    int q = nwg >> 3, r = nwg & 7;
    int xcd = blockIdx.x & 7, jj = blockIdx.x >> 3;
    int t0 = (xcd < r ? xcd * (q + 1) : r * (q + 1) + (xcd - r) * q) + jj;
    int mx = t0 / GN, ny = t0 - mx * GN;

    int tid = threadIdx.x;
    int lane = tid & 63;
    int w = tid >> 6;
    int rowbase = mx * TM;
    int colbase = ny * TN;
    int mwave = (TN == 128) ? (w >> 1) * 64 : w * 32;
    int nwave = (TN == 128) ? (w & 1) * 64 : 0;

    f32x4 acc[MFR][NFR] = {};

    int arow[ACH], asl[ACH];
#pragma unroll
    for (int c = 0; c < ACH; ++c) {
        int idx = c * 256 + tid;
        arow[c] = idx >> 3;
        asl[c] = (idx & 7) ^ (arow[c] & 7);
    }

    int nk = K / BK;
    int ph = blockIdx.x % nk;
    for (int tt = 0; tt < nk; ++tt) {
        int t = tt + ph; if (t >= nk) t -= nk;
        int k0 = t * BK;
#pragma unroll
        for (int c = 0; c < ACH; ++c) {
            int idx = c * 256 + tid;
            int gr = rowbase + arow[c]; if (gr > M - 1) gr = M - 1;
            gload16(A + (size_t)gr * K + k0 + asl[c] * 8, &As[idx * 8]);
        }
#pragma unroll
        for (int c = 0; c < BCH; ++c) {
            int idx = c * 256 + tid;
            int row = idx >> 3, sl = (idx & 7) ^ (row & 7);
            gload16(Bt + (size_t)(colbase + row) * K + k0 + sl * 8, &Bs[idx * 8]);
        }
        __syncthreads();
#pragma unroll
        for (int kh = 0; kh < 2; ++kh) {
            bf16x8 af[MFR], bfr[NFR];
            int ks = (lane >> 4) + kh * 4;
#pragma unroll
            for (int mi = 0; mi < MFR; ++mi) {
                int rr = mwave + mi * 16 + (lane & 15);
                af[mi] = *(const bf16x8*)&As[rr * BK + ((ks ^ (rr & 7)) * 8)];
            }
#pragma unroll
            for (int ni = 0; ni < NFR; ++ni) {
                int rr = nwave + ni * 16 + (lane & 15);
                bfr[ni] = *(const bf16x8*)&Bs[rr * BK + ((ks ^ (rr & 7)) * 8)];
            }
#pragma unroll
            for (int mi = 0; mi < MFR; ++mi)
#pragma unroll
                for (int ni = 0; ni < NFR; ++ni)
                    acc[mi][ni] = __builtin_amdgcn_mfma_f32_16x16x32_bf16(
                        af[mi], bfr[ni], acc[mi][ni], 0, 0, 0);
        }
        __syncthreads();
    }
#pragma unroll
    for (int mi = 0; mi < MFR; ++mi) {
        int r0 = rowbase + mwave + mi * 16 + (lane >> 4) * 4;
#pragma unroll
        for (int ni = 0; ni < NFR; ++ni) {
            int col = colbase + nwave + ni * 16 + (lane & 15);
            float bv = bias[col];
#pragma unroll
            for (int rr = 0; rr < 4; ++rr) {
                int row = r0 + rr;
                if (row < M)
                    C[(size_t)row * Ncols + col] = f2bf(acc[mi][ni][rr] + bv);
            }
        }
    }
}

// ---------------------------------------------------------------------------
// CSR scan + scatter (unchanged)
// ---------------------------------------------------------------------------
__global__ __launch_bounds__(1024)
void scan_deg(const int* __restrict__ deg, int* __restrict__ off,
              int* __restrict__ cur, int N) {
    __shared__ int part[1024];
    int t = threadIdx.x;
    int per = (N + 1023) / 1024;
    int base = t * per;
    int s = 0;
    for (int i = 0; i < per; ++i)
        if (base + i < N) s += deg[base + i];
    part[t] = s;
    __syncthreads();
    for (int d = 1; d < 1024; d <<= 1) {
        int v = (t >= d) ? part[t - d] : 0;
        __syncthreads();
        part[t] += v;
        __syncthreads();
    }
    int excl = (t > 0) ? part[t - 1] : 0;
    for (int i = 0; i < per; ++i) {
        int n = base + i;
        if (n < N) {
            off[n] = excl;
            cur[n] = excl;
            excl += deg[n];
        }
    }
    if (t == 1023) off[N] = part[1023];
}

__global__ __launch_bounds__(256)
void scatter_edges(const int* __restrict__ src, const int* __restrict__ dst,
                   const float* __restrict__ EA, int* __restrict__ cur,
                   int* __restrict__ csrc, float2* __restrict__ caxy, int E) {
    int i = blockIdx.x * 256 + threadIdx.x;
    if (i < E) {
        int p = atomicAdd(&cur[dst[i]], 1);
        csrc[p] = src[i];
        caxy[p] = *(const float2*)(EA + 2 * (size_t)i);
    }
}

// ---------------------------------------------------------------------------
// Head-partitioned per-node attention (layers 1-2, H=4, C=128).
// R15: edge meta (src, ax, ay) read by DIRECT group-uniform loads each trip
// (16 lanes same address -> HW broadcast; CSR arrays are sequential so the
// 4 groups hit 1-2 cache lines). Removes the 64-edge register prefetch, the
// 3 bpermutes/edge, the clamp logic, and the separate overflow path: ONE
// uniform loop over all deg. Predicates stay group-uniform (R5 pattern).
// ---------------------------------------------------------------------------
template <bool RELU>
__global__ __launch_bounds__(256)
void node_attn_h(const u16* __restrict__ QKVS, const int* __restrict__ csrc,
                 const float2* __restrict__ caxy, const float* __restrict__ We,
                 const int* __restrict__ off, u16* __restrict__ OUT,
                 int N, float scale) {
    constexpr int SR = 2048, koff = 512, voff = 1024, skoff = 1536;
    constexpr int HC = 512, C = 128, LPG = 16, NG = 4;
    int h = blockIdx.x;
    int n = blockIdx.y * 4 + (threadIdx.x >> 6);
    if (n >= N) return;
    int lane = threadIdx.x & 63;
    int g = lane >> 4;
    int li = lane & 15;
    int cc = h * C + li * 8;

    const float sc2 = scale * 1.44269504f;
    const u16* nrow = QKVS + (size_t)n * SR;
    bf16x8 q8 = *(const bf16x8*)(nrow + cc);
    float qf[8];
    unpack8(q8, qf);

    float qw0 = 0.f, qw1 = 0.f;
    {
        f32x4 wa = *(const f32x4*)(We + cc), wb = *(const f32x4*)(We + cc + 4);
        f32x4 wc = *(const f32x4*)(We + HC + cc), wd = *(const f32x4*)(We + HC + cc + 4);
#pragma unroll
        for (int j = 0; j < 4; ++j) {
            qw0 = fmaf(qf[j], wa[j], qw0); qw0 = fmaf(qf[4 + j], wb[j], qw0);
            qw1 = fmaf(qf[j], wc[j], qw1); qw1 = fmaf(qf[4 + j], wd[j], qw1);
        }
    }
#pragma unroll
    for (int d = 1; d < LPG; d <<= 1) {
        qw0 += __shfl_xor(qw0, d);
        qw1 += __shfl_xor(qw1, d);
    }
    qw0 *= sc2; qw1 *= sc2;

    int base = off[n];
    int deg = off[n + 1] - base;

    float s = 0.f, A0 = 0.f, A1 = 0.f;
    float acc[8] = {};
    const u16* Kp = QKVS + koff;
    const u16* Vp = QKVS + voff;

    auto process = [&](float ax, float ay, bf16x8 k8, bf16x8 v8) {
        float qk = dot8(q8, k8, 0.f);
#pragma unroll
        for (int d = 1; d < LPG; d <<= 1) qk += __shfl_xor(qk, d);
        float lg2 = fmaf(qk, sc2, fmaf(ax, qw0, ay * qw1));
        lg2 = fminf(lg2, 80.f);
        float p = exp2f(lg2);
        s += p;
        A0 = fmaf(p, ax, A0);
        A1 = fmaf(p, ay, A1);
        float vf[8];
        unpack8(v8, vf);
#pragma unroll
        for (int j = 0; j < 8; ++j) acc[j] = fmaf(p, vf[j], acc[j]);
    };

    // single uniform loop over all deg; meta via group-uniform direct loads
    int trips = (deg + NG - 1) / NG;     // wave-uniform
    int k = 0;
    for (; k + 1 < trips; k += 2) {
        int i0 = g + NG * k, i1 = i0 + NG;
        bool v0 = i0 < deg, v1 = i1 < deg;        // group-uniform
        int a0 = v0 ? i0 : 0, a1 = v1 ? i1 : 0;   // clamped (valid) addrs
        int s0 = csrc[base + a0];
        int s1 = csrc[base + a1];
        float2 e0 = caxy[base + a0];
        float2 e1 = caxy[base + a1];
        bf16x8 ka = *(const bf16x8*)(Kp + (size_t)s0 * SR + cc);
        bf16x8 va = *(const bf16x8*)(Vp + (size_t)s0 * SR + cc);
        bf16x8 kb = *(const bf16x8*)(Kp + (size_t)s1 * SR + cc);
        bf16x8 vb = *(const bf16x8*)(Vp + (size_t)s1 * SR + cc);
        if (v0) process(e0.x, e0.y, ka, va);
        if (v1) process(e1.x, e1.y, kb, vb);
    }
    if (k < trips) {
        int i0 = g + NG * k;
        bool v0 = i0 < deg;
        int a0 = v0 ? i0 : 0;
        int s0 = csrc[base + a0];
        float2 e0 = caxy[base + a0];
        bf16x8 ka = *(const bf16x8*)(Kp + (size_t)s0 * SR + cc);
        bf16x8 va = *(const bf16x8*)(Vp + (size_t)s0 * SR + cc);
        if (v0) process(e0.x, e0.y, ka, va);
    }
    // plain-sum butterfly merge across the 4 edge-groups
#pragma unroll
    for (int d = LPG; d < 64; d <<= 1) {
        s += __shfl_xor(s, d);
        A0 += __shfl_xor(A0, d);
        A1 += __shfl_xor(A1, d);
#pragma unroll
        for (int j = 0; j < 8; ++j) acc[j] += __shfl_xor(acc[j], d);
    }

    if (g == 0) {
        float inv = (s > 0.f) ? 1.f / s : 0.f;
        float sk[8];
        unpack8(*(const bf16x8*)(nrow + skoff + cc), sk);
        f32x4 wa = *(const f32x4*)(We + cc), wb = *(const f32x4*)(We + cc + 4);
        f32x4 wc = *(const f32x4*)(We + HC + cc), wd = *(const f32x4*)(We + HC + cc + 4);
        float w0[8] = {wa[0], wa[1], wa[2], wa[3], wb[0], wb[1], wb[2], wb[3]};
        float w1[8] = {wc[0], wc[1], wc[2], wc[3], wd[0], wd[1], wd[2], wd[3]};
        bf16x8 ov;
#pragma unroll
        for (int j = 0; j < 8; ++j) {
            float agg = (acc[j] + A0 * w0[j] + A1 * w1[j]) * inv;
            float o = agg + sk[j];
            if (RELU) o = fmaxf(o, 0.f);
            ov[j] = (short)f2bf(o);
        }
        *(bf16x8*)(OUT + (size_t)n * 512 + cc) = ov;
    }
}

// ---------------------------------------------------------------------------
// Layer-3 attention (H=1, C=64): same direct-load uniform loop.
// ---------------------------------------------------------------------------
template <int H, int C, int LPG, bool RELU>
__global__ __launch_bounds__(256)
void node_attn(const u16* __restrict__ QKVS, int SR, int koff, int voff,
               int skoff, const int* __restrict__ csrc,
               const float2* __restrict__ caxy, const float* __restrict__ We,
               const int* __restrict__ off, float* __restrict__ OUT,
               int OST, int N, float scale) {
    constexpr int HC = H * C;
    constexpr int NG = 64 / LPG;
    int n = blockIdx.x * 4 + (threadIdx.x >> 6);
    if (n >= N) return;
    int lane = threadIdx.x & 63;
    int g = lane / LPG;
    int li = lane % LPG;
    int cc = li * 8;

    const float sc2 = scale * 1.44269504f;
    const u16* nrow = QKVS + (size_t)n * SR;
    bf16x8 q8 = *(const bf16x8*)(nrow + cc);
    float qf[8];
    unpack8(q8, qf);

    float qw0 = 0.f, qw1 = 0.f;
    {
        f32x4 wa = *(const f32x4*)(We + cc), wb = *(const f32x4*)(We + cc + 4);
        f32x4 wc = *(const f32x4*)(We + HC + cc), wd = *(const f32x4*)(We + HC + cc + 4);
#pragma unroll
        for (int j = 0; j < 4; ++j) {
            qw0 = fmaf(qf[j], wa[j], qw0); qw0 = fmaf(qf[4 + j], wb[j], qw0);
            qw1 = fmaf(qf[j], wc[j], qw1); qw1 = fmaf(qf[4 + j], wd[j], qw1);
        }
    }
#pragma unroll
    for (int d = 1; d < LPG; d <<= 1) {
        qw0 += __shfl_xor(qw0, d);
        qw1 += __shfl_xor(qw1, d);
    }
    qw0 *= sc2; qw1 *= sc2;

    int base = off[n];
    int deg = off[n + 1] - base;

    float s = 0.f, A0 = 0.f, A1 = 0.f;
    float acc[8] = {};
    const u16* Kp = QKVS + koff;
    const u16* Vp = QKVS + voff;

    auto process = [&](float ax, float ay, bf16x8 k8, bf16x8 v8) {
        float qk = dot8(q8, k8, 0.f);
#pragma unroll
        for (int d = 1; d < LPG; d <<= 1) qk += __shfl_xor(qk, d);
        float lg2 = fmaf(qk, sc2, fmaf(ax, qw0, ay * qw1));
        lg2 = fminf(lg2, 80.f);
        float p = exp2f(lg2);
        s += p;
        A0 = fmaf(p, ax, A0);
        A1 = fmaf(p, ay, A1);
        float vf[8];
        unpack8(v8, vf);
#pragma unroll
        for (int j = 0; j < 8; ++j) acc[j] = fmaf(p, vf[j], acc[j]);
    };

    int trips = (deg + NG - 1) / NG;
    int k = 0;
    for (; k + 1 < trips; k += 2) {
        int i0 = g + NG * k, i1 = i0 + NG;
        bool v0 = i0 < deg, v1 = i1 < deg;
        int a0 = v0 ? i0 : 0, a1 = v1 ? i1 : 0;
        int s0 = csrc[base + a0];
        int s1 = csrc[base + a1];
        float2 e0 = caxy[base + a0];
        float2 e1 = caxy[base + a1];
        bf16x8 ka = *(const bf16x8*)(Kp + (size_t)s0 * SR + cc);
        bf16x8 va = *(const bf16x8*)(Vp + (size_t)s0 * SR + cc);
        bf16x8 kb = *(const bf16x8*)(Kp + (size_t)s1 * SR + cc);
        bf16x8 vb = *(const bf16x8*)(Vp + (size_t)s1 * SR + cc);
        if (v0) process(e0.x, e0.y, ka, va);
        if (v1) process(e1.x, e1.y, kb, vb);
    }
    if (k < trips) {
        int i0 = g + NG * k;
        bool v0 = i0 < deg;
        int a0 = v0 ? i0 : 0;
        int s0 = csrc[base + a0];
        float2 e0 = caxy[base + a0];
        bf16x8 ka = *(const bf16x8*)(Kp + (size_t)s0 * SR + cc);
        bf16x8 va = *(const bf16x8*)(Vp + (size_t)s0 * SR + cc);
        if (v0) process(e0.x, e0.y, ka, va);
    }
#pragma unroll
    for (int d = LPG; d < 64; d <<= 1) {
        s += __shfl_xor(s, d);
        A0 += __shfl_xor(A0, d);
        A1 += __shfl_xor(A1, d);
#pragma unroll
        for (int j = 0; j < 8; ++j) acc[j] += __shfl_xor(acc[j], d);
    }

    if (g == 0) {
        float inv = (s > 0.f) ? 1.f / s : 0.f;
        float sk[8];
        unpack8(*(const bf16x8*)(nrow + skoff + cc), sk);
        f32x4 wa = *(const f32x4*)(We + cc), wb = *(const f32x4*)(We + cc + 4);
        f32x4 wc = *(const f32x4*)(We + HC + cc), wd = *(const f32x4*)(We + HC + cc + 4);
        float w0[8] = {wa[0], wa[1], wa[2], wa[3], wb[0], wb[1], wb[2], wb[3]};
        float w1[8] = {wc[0], wc[1], wc[2], wc[3], wd[0], wd[1], wd[2], wd[3]};
        float o[8];
#pragma unroll
        for (int j = 0; j < 8; ++j) {
            float agg = (acc[j] + A0 * w0[j] + A1 * w1[j]) * inv;
            o[j] = agg + sk[j];
            if (RELU) o[j] = fmaxf(o[j], 0.f);
        }
        f32x4 oa = {o[0], o[1], o[2], o[3]}, ob = {o[4], o[5], o[6], o[7]};
        *(f32x4*)(OUT + (size_t)n * OST + cc) = oa;
        *(f32x4*)(OUT + (size_t)n * OST + cc + 4) = ob;
    }
}

// ---------------------------------------------------------------------------
extern "C" void kernel_launch(void* const* d_in, const int* in_sizes, int n_in,
                              void* d_out, int out_size, void* d_ws, size_t ws_size,
                              hipStream_t stream) {
    const float* x  = (const float*)d_in[0];
    const int* esrc = (const int*)d_in[1];
    const int* edst = (const int*)d_in[2];
    const float* ea = (const float*)d_in[3];
    const int N = in_sizes[0] / 5;
    const int E = in_sizes[1];
    auto in = [&](int i) { return (const float*)d_in[i]; };

    char* p = (char*)d_ws;
    auto alloc = [&](size_t b) {
        char* r = p; p += (b + 255) & ~(size_t)255; return (void*)r;
    };
    u16* QKVS  = (u16*)alloc((size_t)N * 2048 * 2);
    u16* HB    = (u16*)alloc((size_t)N * 512 * 2);
    u16* Wt2   = (u16*)alloc((size_t)2048 * 512 * 2);
    u16* Wt3   = (u16*)alloc((size_t)256 * 512 * 2);
    float* b2  = (float*)alloc(2048 * 4);
    float* b3  = (float*)alloc(256 * 4);
    int* deg   = (int*)alloc((size_t)N * 4);
    int* off   = (int*)alloc((size_t)(N + 1) * 4);
    int* cur   = (int*)alloc((size_t)N * 4);
    int* csrc  = (int*)alloc((size_t)E * 4);
    float2* caxy = (float2*)alloc((size_t)E * 8);

    dim3 b256(256);
    int gE256 = (E + 255) / 256;
    int gM = (N + 127) / 128;
    int gA = (N + 3) / 4;
    const float scale128 = 0.08838834764831845f;
    const float scale64  = 0.125f;

    // ---- fused setup: histogram | weight prep | layer-1 GEMM ----
    hipMemsetAsync(deg, 0, (size_t)N * sizeof(int), stream);
    PrepArgs pa = {{in(13), in(15), in(17), in(20), in(22), in(24), in(26), in(29)},
                   {in(14), in(16), in(18), in(21), in(23), in(25), in(27), in(30)}};
    Ptr8 l1 = {{in(4), in(6), in(8), in(11), in(5), in(7), in(9), in(12)}};
    int gSetup = gE256 + 2304 + (N + 31) / 32;
    setup_fused<<<dim3(gSetup), b256, 0, stream>>>(
        edst, deg, E, pa, Wt2, Wt3, b2, b3, x, l1, QKVS, N);

    // ---- CSR finalize ----
    scan_deg<<<1, 1024, 0, stream>>>(deg, off, cur, N);
    scatter_edges<<<gE256, b256, 0, stream>>>(esrc, edst, ea, cur, csrc, caxy, E);

    // ---- Layer 1 attention ----
    node_attn_h<true><<<dim3(4, gA), b256, 0, stream>>>(
        QKVS, csrc, caxy, in(10), off, HB, N, scale128);

    // ---- Layer 2 ----
    gemm_bf16<128, 16><<<dim3(gM * 16), b256, 0, stream>>>(HB, Wt2, b2, QKVS, N, 2048, 512);
    node_attn_h<true><<<dim3(4, gA), b256, 0, stream>>>(
        QKVS, csrc, caxy, in(19), off, HB, N, scale128);

    // ---- Layer 3 ----
    gemm_bf16<64, 4><<<dim3(gM * 4), b256, 0, stream>>>(HB, Wt3, b3, QKVS, N, 256, 512);
    node_attn<1, 64, 8, false><<<dim3(gA), b256, 0, stream>>>(
        QKVS, 256, 64, 128, 192, csrc, caxy, in(28), off,
        (float*)d_out, 64, N, scale64);
}

// Round 16
// 201.285 us; speedup vs baseline: 1.0263x; 1.0263x over previous
//
#include <hip/hip_runtime.h>

typedef unsigned short u16;
typedef __attribute__((ext_vector_type(8))) short bf16x8;
typedef __attribute__((ext_vector_type(4))) float f32x4;

__device__ __forceinline__ float bf2f(u16 s) {
    return __uint_as_float(((unsigned)s) << 16);
}
__device__ __forceinline__ u16 f2bf(float f) {
    unsigned u = __float_as_uint(f);
    u += 0x7fff + ((u >> 16) & 1);   // RNE
    return (u16)(u >> 16);
}
__device__ __forceinline__ void unpack8(bf16x8 x, float* f) {
#pragma unroll
    for (int j = 0; j < 8; ++j) f[j] = bf2f((u16)x[j]);
}

// async 16B global -> LDS (linear dest: uniform base + lane*16)
__device__ __forceinline__ void gload16(const u16* g, u16* l) {
    __builtin_amdgcn_global_load_lds(
        (const __attribute__((address_space(1))) unsigned*)g,
        (__attribute__((address_space(3))) unsigned*)l, 16, 0, 0);
}

// q.k dot over 8 packed bf16; fdot2 when available.
__device__ __forceinline__ float dot8(bf16x8 a, bf16x8 b, float c) {
#if __has_builtin(__builtin_amdgcn_fdot2_f32_bf16)
    typedef __attribute__((ext_vector_type(2))) __bf16 bf16x2;
    union U { bf16x8 v; bf16x2 p[4]; };
    U ua, ub; ua.v = a; ub.v = b;
#pragma unroll
    for (int i = 0; i < 4; ++i)
        c = __builtin_amdgcn_fdot2_f32_bf16(ua.p[i], ub.p[i], c, false);
    return c;
#else
    float fa[8], fb[8];
    unpack8(a, fa); unpack8(b, fb);
#pragma unroll
    for (int j = 0; j < 8; ++j) c = fmaf(fa[j], fb[j], c);
    return c;
#endif
}

struct Ptr8 { const float* p[8]; };
struct PrepArgs { const float* w[8]; const float* b[8]; };

// ---------------------------------------------------------------------------
// FUSED setup kernel: histogram | weight prep | L1 GEMM (R14 known-good)
// ---------------------------------------------------------------------------
__global__ __launch_bounds__(256)
void setup_fused(const int* __restrict__ edst, int* __restrict__ deg, int E,
                 PrepArgs a, u16* __restrict__ Wt2, u16* __restrict__ Wt3,
                 float* __restrict__ b2, float* __restrict__ b3,
                 const float* __restrict__ X, Ptr8 wb,
                 u16* __restrict__ OUT, int N) {
    int b = blockIdx.x;
    int nh = (E + 255) / 256;
    if (b < nh) {
        int i = b * 256 + threadIdx.x;
        if (i < E) atomicAdd(&deg[edst[i]], 1);
        return;
    }
    b -= nh;
    if (b < 2304) {
        int z = b >> 8, rem = b & 255;
        int bx = rem & 15, by = rem >> 4;
        if (z == 8) {
            if (by != 0 || bx >= 9) return;
            int j = bx * 256 + threadIdx.x;
            if (j < 2048) b2[j] = a.b[j >> 9][j & 511];
            else if (j < 2304) { int jj = j - 2048; b3[jj] = a.b[4 + (jj >> 6)][jj & 63]; }
            return;
        }
        const float* in;
        u16* out;
        int Nw;
        if (z < 4) { in = a.w[z]; out = Wt2 + (size_t)z * 512 * 512; Nw = 512; }
        else {
            if (by >= 2) return;
            in = a.w[z]; out = Wt3 + (size_t)(z - 4) * 64 * 512; Nw = 64;
        }
        __shared__ float t[32][33];
        int kb = bx * 32, nb = by * 32;
        int tx = threadIdx.x & 31, ty = threadIdx.x >> 5;
#pragma unroll
        for (int r = ty; r < 32; r += 8)
            if (nb + tx < Nw)
                t[r][tx] = in[(size_t)(kb + r) * Nw + nb + tx];
        __syncthreads();
#pragma unroll
        for (int r = ty; r < 32; r += 8)
            if (nb + r < Nw)
                out[(size_t)(nb + r) * 512 + kb + tx] = f2bf(t[tx][r]);
        return;
    }
    b -= 2304;
    int wsel = threadIdx.x >> 6;
    int jj = (threadIdx.x & 63) * 8;
    const float* W = wb.p[wsel];
    const float* bb = wb.p[4 + wsel];
    float w[5][8], bs[8];
#pragma unroll
    for (int i = 0; i < 5; ++i)
#pragma unroll
        for (int j = 0; j < 8; ++j) w[i][j] = W[(size_t)i * 512 + jj + j];
#pragma unroll
    for (int j = 0; j < 8; ++j) bs[j] = bb[jj + j];
    int n0 = b * 32;
    int nend = (N - n0 < 32) ? (N - n0) : 32;
    for (int i = 0; i < nend; ++i) {
        int n = n0 + i;
        float xr[5];
#pragma unroll
        for (int k = 0; k < 5; ++k) xr[k] = X[(size_t)n * 5 + k];
        float acc[8];
#pragma unroll
        for (int j = 0; j < 8; ++j) acc[j] = bs[j];
#pragma unroll
        for (int k = 0; k < 5; ++k)
#pragma unroll
            for (int j = 0; j < 8; ++j) acc[j] = fmaf(xr[k], w[k][j], acc[j]);
        bf16x8 o;
#pragma unroll
        for (int j = 0; j < 8; ++j) o[j] = (short)f2bf(acc[j]);
        *(bf16x8*)(OUT + (size_t)n * 2048 + wsel * 512 + jj) = o;
    }
}

// ---------------------------------------------------------------------------
// bf16 MFMA GEMM (R14 known-good: single-buffer + K-phase stagger +
// m204 XCD chunking + pre-swizzled-source global_load_lds)
// ---------------------------------------------------------------------------
template <int TN, int GN>
__global__ __launch_bounds__(256)
void gemm_bf16(const u16* __restrict__ A, const u16* __restrict__ Bt,
               const float* __restrict__ bias, u16* __restrict__ C,
               int M, int Ncols, int K) {
    constexpr int TM = 128, BK = 64;
    constexpr int MFR = (TN == 128) ? 4 : 2;
    constexpr int NFR = 4;
    constexpr int ACH = TM * BK / (256 * 8);
    constexpr int BCH = TN * BK / (256 * 8);

    __shared__ u16 As[TM * BK];
    __shared__ u16 Bs[TN * BK];

    int nwg = gridDim.x;
    int q = nwg >> 3, r = nwg & 7;
    int xcd = blockIdx.x & 7, jj = blockIdx.x >> 3;
    int t0 = (xcd < r ? xcd * (q + 1) : r * (q + 1) + (xcd - r) * q) + jj;
    int mx = t0 / GN, ny = t0 - mx * GN;

    int tid = threadIdx.x;
    int lane = tid & 63;
    int w = tid >> 6;
    int rowbase = mx * TM;
    int colbase = ny * TN;
    int mwave = (TN == 128) ? (w >> 1) * 64 : w * 32;
    int nwave = (TN == 128) ? (w & 1) * 64 : 0;

    f32x4 acc[MFR][NFR] = {};

    int arow[ACH], asl[ACH];
#pragma unroll
    for (int c = 0; c < ACH; ++c) {
        int idx = c * 256 + tid;
        arow[c] = idx >> 3;
        asl[c] = (idx & 7) ^ (arow[c] & 7);
    }

    int nk = K / BK;
    int ph = blockIdx.x % nk;
    for (int tt = 0; tt < nk; ++tt) {
        int t = tt + ph; if (t >= nk) t -= nk;
        int k0 = t * BK;
#pragma unroll
        for (int c = 0; c < ACH; ++c) {
            int idx = c * 256 + tid;
            int gr = rowbase + arow[c]; if (gr > M - 1) gr = M - 1;
            gload16(A + (size_t)gr * K + k0 + asl[c] * 8, &As[idx * 8]);
        }
#pragma unroll
        for (int c = 0; c < BCH; ++c) {
            int idx = c * 256 + tid;
            int row = idx >> 3, sl = (idx & 7) ^ (row & 7);
            gload16(Bt + (size_t)(colbase + row) * K + k0 + sl * 8, &Bs[idx * 8]);
        }
        __syncthreads();
#pragma unroll
        for (int kh = 0; kh < 2; ++kh) {
            bf16x8 af[MFR], bfr[NFR];
            int ks = (lane >> 4) + kh * 4;
#pragma unroll
            for (int mi = 0; mi < MFR; ++mi) {
                int rr = mwave + mi * 16 + (lane & 15);
                af[mi] = *(const bf16x8*)&As[rr * BK + ((ks ^ (rr & 7)) * 8)];
            }
#pragma unroll
            for (int ni = 0; ni < NFR; ++ni) {
                int rr = nwave + ni * 16 + (lane & 15);
                bfr[ni] = *(const bf16x8*)&Bs[rr * BK + ((ks ^ (rr & 7)) * 8)];
            }
#pragma unroll
            for (int mi = 0; mi < MFR; ++mi)
#pragma unroll
                for (int ni = 0; ni < NFR; ++ni)
                    acc[mi][ni] = __builtin_amdgcn_mfma_f32_16x16x32_bf16(
                        af[mi], bfr[ni], acc[mi][ni], 0, 0, 0);
        }
        __syncthreads();
    }
#pragma unroll
    for (int mi = 0; mi < MFR; ++mi) {
        int r0 = rowbase + mwave + mi * 16 + (lane >> 4) * 4;
#pragma unroll
        for (int ni = 0; ni < NFR; ++ni) {
            int col = colbase + nwave + ni * 16 + (lane & 15);
            float bv = bias[col];
#pragma unroll
            for (int rr = 0; rr < 4; ++rr) {
                int row = r0 + rr;
                if (row < M)
                    C[(size_t)row * Ncols + col] = f2bf(acc[mi][ni][rr] + bv);
            }
        }
    }
}

// ---------------------------------------------------------------------------
// CSR scan + scatter (unchanged)
// ---------------------------------------------------------------------------
__global__ __launch_bounds__(1024)
void scan_deg(const int* __restrict__ deg, int* __restrict__ off,
              int* __restrict__ cur, int N) {
    __shared__ int part[1024];
    int t = threadIdx.x;
    int per = (N + 1023) / 1024;
    int base = t * per;
    int s = 0;
    for (int i = 0; i < per; ++i)
        if (base + i < N) s += deg[base + i];
    part[t] = s;
    __syncthreads();
    for (int d = 1; d < 1024; d <<= 1) {
        int v = (t >= d) ? part[t - d] : 0;
        __syncthreads();
        part[t] += v;
        __syncthreads();
    }
    int excl = (t > 0) ? part[t - 1] : 0;
    for (int i = 0; i < per; ++i) {
        int n = base + i;
        if (n < N) {
            off[n] = excl;
            cur[n] = excl;
            excl += deg[n];
        }
    }
    if (t == 1023) off[N] = part[1023];
}

__global__ __launch_bounds__(256)
void scatter_edges(const int* __restrict__ src, const int* __restrict__ dst,
                   const float* __restrict__ EA, int* __restrict__ cur,
                   int* __restrict__ csrc, float2* __restrict__ caxy, int E) {
    int i = blockIdx.x * 256 + threadIdx.x;
    if (i < E) {
        int p = atomicAdd(&cur[dst[i]], 1);
        csrc[p] = src[i];
        caxy[p] = *(const float2*)(EA + 2 * (size_t)i);
    }
}

// ---------------------------------------------------------------------------
// Head-partitioned per-node attention (layers 1-2, H=4, C=128) — R14
// known-best: 64-edge register prefetch + clamped-shfl broadcast (meta off
// the memory critical path), 2x-unrolled gathers (4 in flight), rare
// overflow path. R15's direct-load variant regressed (dependent meta load
// on the chain); reverted.
// ---------------------------------------------------------------------------
template <bool RELU>
__global__ __launch_bounds__(256)
void node_attn_h(const u16* __restrict__ QKVS, const int* __restrict__ csrc,
                 const float2* __restrict__ caxy, const float* __restrict__ We,
                 const int* __restrict__ off, u16* __restrict__ OUT,
                 int N, float scale) {
    constexpr int SR = 2048, koff = 512, voff = 1024, skoff = 1536;
    constexpr int HC = 512, C = 128, LPG = 16, NG = 4;
    int h = blockIdx.x;
    int n = blockIdx.y * 4 + (threadIdx.x >> 6);
    if (n >= N) return;
    int lane = threadIdx.x & 63;
    int g = lane >> 4;
    int li = lane & 15;
    int cc = h * C + li * 8;

    const float sc2 = scale * 1.44269504f;
    const u16* nrow = QKVS + (size_t)n * SR;
    bf16x8 q8 = *(const bf16x8*)(nrow + cc);
    float qf[8];
    unpack8(q8, qf);

    float qw0 = 0.f, qw1 = 0.f;
    {
        f32x4 wa = *(const f32x4*)(We + cc), wb = *(const f32x4*)(We + cc + 4);
        f32x4 wc = *(const f32x4*)(We + HC + cc), wd = *(const f32x4*)(We + HC + cc + 4);
#pragma unroll
        for (int j = 0; j < 4; ++j) {
            qw0 = fmaf(qf[j], wa[j], qw0); qw0 = fmaf(qf[4 + j], wb[j], qw0);
            qw1 = fmaf(qf[j], wc[j], qw1); qw1 = fmaf(qf[4 + j], wd[j], qw1);
        }
    }
#pragma unroll
    for (int d = 1; d < LPG; d <<= 1) {
        qw0 += __shfl_xor(qw0, d);
        qw1 += __shfl_xor(qw1, d);
    }
    qw0 *= sc2; qw1 *= sc2;

    int base = off[n];
    int deg = off[n + 1] - base;
    int pdeg = deg < 64 ? deg : 64;
    int ps = 0; float pax = 0.f, pay = 0.f;
    if (lane < pdeg) {
        ps = csrc[base + lane];
        float2 a = caxy[base + lane];
        pax = a.x; pay = a.y;
    }

    float s = 0.f, A0 = 0.f, A1 = 0.f;
    float acc[8] = {};
    const u16* Kp = QKVS + koff;
    const u16* Vp = QKVS + voff;

    auto process = [&](float ax, float ay, bf16x8 k8, bf16x8 v8) {
        float qk = dot8(q8, k8, 0.f);
#pragma unroll
        for (int d = 1; d < LPG; d <<= 1) qk += __shfl_xor(qk, d);
        float lg2 = fmaf(qk, sc2, fmaf(ax, qw0, ay * qw1));
        lg2 = fminf(lg2, 80.f);
        float p = exp2f(lg2);
        s += p;
        A0 = fmaf(p, ax, A0);
        A1 = fmaf(p, ay, A1);
        float vf[8];
        unpack8(v8, vf);
#pragma unroll
        for (int j = 0; j < 8; ++j) acc[j] = fmaf(p, vf[j], acc[j]);
    };

    int trips = (pdeg + NG - 1) / NG;
    int k = 0;
    for (; k + 1 < trips; k += 2) {
        int i0 = g + NG * k, i1 = i0 + NG;
        bool v0 = i0 < pdeg, v1 = i1 < pdeg;
        int si0 = v0 ? i0 : 0, si1 = v1 ? i1 : 0;
        int s0 = __shfl(ps, si0);
        int s1 = __shfl(ps, si1);
        float ax0 = __shfl(pax, si0), ay0 = __shfl(pay, si0);
        float ax1 = __shfl(pax, si1), ay1 = __shfl(pay, si1);
        bf16x8 ka = *(const bf16x8*)(Kp + (size_t)s0 * SR + cc);
        bf16x8 va = *(const bf16x8*)(Vp + (size_t)s0 * SR + cc);
        bf16x8 kb = *(const bf16x8*)(Kp + (size_t)s1 * SR + cc);
        bf16x8 vb = *(const bf16x8*)(Vp + (size_t)s1 * SR + cc);
        if (v0) process(ax0, ay0, ka, va);
        if (v1) process(ax1, ay1, kb, vb);
    }
    if (k < trips) {
        int i0 = g + NG * k;
        bool v0 = i0 < pdeg;
        int si0 = v0 ? i0 : 0;
        int s0 = __shfl(ps, si0);
        float ax0 = __shfl(pax, si0), ay0 = __shfl(pay, si0);
        bf16x8 ka = *(const bf16x8*)(Kp + (size_t)s0 * SR + cc);
        bf16x8 va = *(const bf16x8*)(Vp + (size_t)s0 * SR + cc);
        if (v0) process(ax0, ay0, ka, va);
    }
    int otr = (deg > 64) ? (deg - 64 + NG - 1) / NG : 0;
    for (int kk = 0; kk < otr; ++kk) {
        int idx = 64 + NG * kk + g;
        bool valid = idx < deg;
        int ii = valid ? idx : (deg - 1);
        int s0 = csrc[base + ii];
        float2 a = caxy[base + ii];
        bf16x8 k0 = *(const bf16x8*)(Kp + (size_t)s0 * SR + cc);
        bf16x8 v0 = *(const bf16x8*)(Vp + (size_t)s0 * SR + cc);
        if (valid) process(a.x, a.y, k0, v0);
    }
#pragma unroll
    for (int d = LPG; d < 64; d <<= 1) {
        s += __shfl_xor(s, d);
        A0 += __shfl_xor(A0, d);
        A1 += __shfl_xor(A1, d);
#pragma unroll
        for (int j = 0; j < 8; ++j) acc[j] += __shfl_xor(acc[j], d);
    }

    if (g == 0) {
        float inv = (s > 0.f) ? 1.f / s : 0.f;
        float sk[8];
        unpack8(*(const bf16x8*)(nrow + skoff + cc), sk);
        f32x4 wa = *(const f32x4*)(We + cc), wb = *(const f32x4*)(We + cc + 4);
        f32x4 wc = *(const f32x4*)(We + HC + cc), wd = *(const f32x4*)(We + HC + cc + 4);
        float w0[8] = {wa[0], wa[1], wa[2], wa[3], wb[0], wb[1], wb[2], wb[3]};
        float w1[8] = {wc[0], wc[1], wc[2], wc[3], wd[0], wd[1], wd[2], wd[3]};
        bf16x8 ov;
#pragma unroll
        for (int j = 0; j < 8; ++j) {
            float agg = (acc[j] + A0 * w0[j] + A1 * w1[j]) * inv;
            float o = agg + sk[j];
            if (RELU) o = fmaxf(o, 0.f);
            ov[j] = (short)f2bf(o);
        }
        *(bf16x8*)(OUT + (size_t)n * 512 + cc) = ov;
    }
}

// ---------------------------------------------------------------------------
// Layer-3 attention (H=1, C=64): R14 known-best form.
// ---------------------------------------------------------------------------
template <int H, int C, int LPG, bool RELU>
__global__ __launch_bounds__(256)
void node_attn(const u16* __restrict__ QKVS, int SR, int koff, int voff,
               int skoff, const int* __restrict__ csrc,
               const float2* __restrict__ caxy, const float* __restrict__ We,
               const int* __restrict__ off, float* __restrict__ OUT,
               int OST, int N, float scale) {
    constexpr int HC = H * C;
    constexpr int NG = 64 / LPG;
    int n = blockIdx.x * 4 + (threadIdx.x >> 6);
    if (n >= N) return;
    int lane = threadIdx.x & 63;
    int g = lane / LPG;
    int li = lane % LPG;
    int cc = li * 8;

    const float sc2 = scale * 1.44269504f;
    const u16* nrow = QKVS + (size_t)n * SR;
    bf16x8 q8 = *(const bf16x8*)(nrow + cc);
    float qf[8];
    unpack8(q8, qf);

    float qw0 = 0.f, qw1 = 0.f;
    {
        f32x4 wa = *(const f32x4*)(We + cc), wb = *(const f32x4*)(We + cc + 4);
        f32x4 wc = *(const f32x4*)(We + HC + cc), wd = *(const f32x4*)(We + HC + cc + 4);
#pragma unroll
        for (int j = 0; j < 4; ++j) {
            qw0 = fmaf(qf[j], wa[j], qw0); qw0 = fmaf(qf[4 + j], wb[j], qw0);
            qw1 = fmaf(qf[j], wc[j], qw1); qw1 = fmaf(qf[4 + j], wd[j], qw1);
        }
    }
#pragma unroll
    for (int d = 1; d < LPG; d <<= 1) {
        qw0 += __shfl_xor(qw0, d);
        qw1 += __shfl_xor(qw1, d);
    }
    qw0 *= sc2; qw1 *= sc2;

    int base = off[n];
    int deg = off[n + 1] - base;
    int pdeg = deg < 64 ? deg : 64;
    int ps = 0; float pax = 0.f, pay = 0.f;
    if (lane < pdeg) {
        ps = csrc[base + lane];
        float2 a = caxy[base + lane];
        pax = a.x; pay = a.y;
    }

    float s = 0.f, A0 = 0.f, A1 = 0.f;
    float acc[8] = {};
    const u16* Kp = QKVS + koff;
    const u16* Vp = QKVS + voff;

    auto process = [&](float ax, float ay, bf16x8 k8, bf16x8 v8) {
        float qk = dot8(q8, k8, 0.f);
#pragma unroll
        for (int d = 1; d < LPG; d <<= 1) qk += __shfl_xor(qk, d);
        float lg2 = fmaf(qk, sc2, fmaf(ax, qw0, ay * qw1));
        lg2 = fminf(lg2, 80.f);
        float p = exp2f(lg2);
        s += p;
        A0 = fmaf(p, ax, A0);
        A1 = fmaf(p, ay, A1);
        float vf[8];
        unpack8(v8, vf);
#pragma unroll
        for (int j = 0; j < 8; ++j) acc[j] = fmaf(p, vf[j], acc[j]);
    };

    int trips = (pdeg + NG - 1) / NG;
    for (int k = 0; k < trips; ++k) {
        int idx = g + NG * k;
        bool valid = idx < pdeg;
        int sidx = valid ? idx : (pdeg - 1);
        int s0 = __shfl(ps, sidx);
        float ax0 = __shfl(pax, sidx), ay0 = __shfl(pay, sidx);
        bf16x8 k0 = *(const bf16x8*)(Kp + (size_t)s0 * SR + cc);
        bf16x8 v0 = *(const bf16x8*)(Vp + (size_t)s0 * SR + cc);
        if (valid) process(ax0, ay0, k0, v0);
    }
    int otr = (deg > 64) ? (deg - 64 + NG - 1) / NG : 0;
    for (int k = 0; k < otr; ++k) {
        int idx = 64 + NG * k + g;
        bool valid = idx < deg;
        int ii = valid ? idx : (deg - 1);
        int s0 = csrc[base + ii];
        float2 a = caxy[base + ii];
        bf16x8 k0 = *(const bf16x8*)(Kp + (size_t)s0 * SR + cc);
        bf16x8 v0 = *(const bf16x8*)(Vp + (size_t)s0 * SR + cc);
        if (valid) process(a.x, a.y, k0, v0);
    }
#pragma unroll
    for (int d = LPG; d < 64; d <<= 1) {
        s += __shfl_xor(s, d);
        A0 += __shfl_xor(A0, d);
        A1 += __shfl_xor(A1, d);
#pragma unroll
        for (int j = 0; j < 8; ++j) acc[j] += __shfl_xor(acc[j], d);
    }

    if (g == 0) {
        float inv = (s > 0.f) ? 1.f / s : 0.f;
        float sk[8];
        unpack8(*(const bf16x8*)(nrow + skoff + cc), sk);
        f32x4 wa = *(const f32x4*)(We + cc), wb = *(const f32x4*)(We + cc + 4);
        f32x4 wc = *(const f32x4*)(We + HC + cc), wd = *(const f32x4*)(We + HC + cc + 4);
        float w0[8] = {wa[0], wa[1], wa[2], wa[3], wb[0], wb[1], wb[2], wb[3]};
        float w1[8] = {wc[0], wc[1], wc[2], wc[3], wd[0], wd[1], wd[2], wd[3]};
        float o[8];
#pragma unroll
        for (int j = 0; j < 8; ++j) {
            float agg = (acc[j] + A0 * w0[j] + A1 * w1[j]) * inv;
            o[j] = agg + sk[j];
            if (RELU) o[j] = fmaxf(o[j], 0.f);
        }
        f32x4 oa = {o[0], o[1], o[2], o[3]}, ob = {o[4], o[5], o[6], o[7]};
        *(f32x4*)(OUT + (size_t)n * OST + cc) = oa;
        *(f32x4*)(OUT + (size_t)n * OST + cc + 4) = ob;
    }
}

// ---------------------------------------------------------------------------
extern "C" void kernel_launch(void* const* d_in, const int* in_sizes, int n_in,
                              void* d_out, int out_size, void* d_ws, size_t ws_size,
                              hipStream_t stream) {
    const float* x  = (const float*)d_in[0];
    const int* esrc = (const int*)d_in[1];
    const int* edst = (const int*)d_in[2];
    const float* ea = (const float*)d_in[3];
    const int N = in_sizes[0] / 5;
    const int E = in_sizes[1];
    auto in = [&](int i) { return (const float*)d_in[i]; };

    char* p = (char*)d_ws;
    auto alloc = [&](size_t b) {
        char* r = p; p += (b + 255) & ~(size_t)255; return (void*)r;
    };
    u16* QKVS  = (u16*)alloc((size_t)N * 2048 * 2);
    u16* HB    = (u16*)alloc((size_t)N * 512 * 2);
    u16* Wt2   = (u16*)alloc((size_t)2048 * 512 * 2);
    u16* Wt3   = (u16*)alloc((size_t)256 * 512 * 2);
    float* b2  = (float*)alloc(2048 * 4);
    float* b3  = (float*)alloc(256 * 4);
    int* deg   = (int*)alloc((size_t)N * 4);
    int* off   = (int*)alloc((size_t)(N + 1) * 4);
    int* cur   = (int*)alloc((size_t)N * 4);
    int* csrc  = (int*)alloc((size_t)E * 4);
    float2* caxy = (float2*)alloc((size_t)E * 8);

    dim3 b256(256);
    int gE256 = (E + 255) / 256;
    int gM = (N + 127) / 128;
    int gA = (N + 3) / 4;
    const float scale128 = 0.08838834764831845f;
    const float scale64  = 0.125f;

    // ---- fused setup: histogram | weight prep | layer-1 GEMM ----
    hipMemsetAsync(deg, 0, (size_t)N * sizeof(int), stream);
    PrepArgs pa = {{in(13), in(15), in(17), in(20), in(22), in(24), in(26), in(29)},
                   {in(14), in(16), in(18), in(21), in(23), in(25), in(27), in(30)}};
    Ptr8 l1 = {{in(4), in(6), in(8), in(11), in(5), in(7), in(9), in(12)}};
    int gSetup = gE256 + 2304 + (N + 31) / 32;
    setup_fused<<<dim3(gSetup), b256, 0, stream>>>(
        edst, deg, E, pa, Wt2, Wt3, b2, b3, x, l1, QKVS, N);

    // ---- CSR finalize ----
    scan_deg<<<1, 1024, 0, stream>>>(deg, off, cur, N);
    scatter_edges<<<gE256, b256, 0, stream>>>(esrc, edst, ea, cur, csrc, caxy, E);

    // ---- Layer 1 attention ----
    node_attn_h<true><<<dim3(4, gA), b256, 0, stream>>>(
        QKVS, csrc, caxy, in(10), off, HB, N, scale128);

    // ---- Layer 2 ----
    gemm_bf16<128, 16><<<dim3(gM * 16), b256, 0, stream>>>(HB, Wt2, b2, QKVS, N, 2048, 512);
    node_attn_h<true><<<dim3(4, gA), b256, 0, stream>>>(
        QKVS, csrc, caxy, in(19), off, HB, N, scale128);

    // ---- Layer 3 ----
    gemm_bf16<64, 4><<<dim3(gM * 4), b256, 0, stream>>>(HB, Wt3, b3, QKVS, N, 256, 512);
    node_attn<1, 64, 8, false><<<dim3(gA), b256, 0, stream>>>(
        QKVS, 256, 64, 128, 192, csrc, caxy, in(28), off,
        (float*)d_out, 64, N, scale64);
}